// Round 22
// baseline (125.360 us; speedup 1.0000x reference)
//
#include <hip/hip_runtime.h>
#include <stdint.h>

#define NB 8
#define NH 96
#define NW_ 96
#define NA 9
#define NANCH (NH * NW_ * NA)   // 82944
#define KPRE 4000
#define MAXOUT 2000
#define KEYCAP 4224             // >= KPRE + max expected cut-bucket size
#define NWORDS 63               // ceil(4000/64)
#define GTASKS 528              // per batch: sum_c ceil((63-c)/4)
#define EB_CAP 2048             // edges per (batch, i-chunk) bucket (global)
#define ELTOT 8192              // flat edge capacity per batch (32 KB LDS)
#define HBLK 8                  // histogram blocks per batch
#define CBLK 32                 // collect blocks per batch

typedef unsigned long long u64;

__device__ __forceinline__ u64 readlane64(u64 v, int l) {
    unsigned lo = (unsigned)__builtin_amdgcn_readlane((int)(unsigned)v, l);
    unsigned hi = (unsigned)__builtin_amdgcn_readlane((int)(unsigned)(v >> 32), l);
    return ((u64)hi << 32) | lo;
}
__device__ __forceinline__ float readlane_f(float v, int l) {
    return __uint_as_float((unsigned)__builtin_amdgcn_readlane((int)__float_as_uint(v), l));
}

// ------- Kernel 1: per-block partial histograms (pure stores, no memset) -----
__global__ __launch_bounds__(256) void k_hist(const float* __restrict__ score,
                                              unsigned* __restrict__ phist) {
    const int b = blockIdx.y;
    const int g = blockIdx.x;
    __shared__ unsigned h[4096];
    for (int i = threadIdx.x; i < 4096; i += 256) h[i] = 0u;
    __syncthreads();
    const float4* s4 = (const float4*)(score + (size_t)b * NANCH);
    int i0 = g * 256 + threadIdx.x;
    const int stride = HBLK * 256;
    for (int i = i0; i < NANCH / 4; i += stride) {
        float4 v = s4[i];
        if (v.x > 0.5f) atomicAdd(&h[(__float_as_uint(v.x) >> 11) & 4095u], 1u);
        if (v.y > 0.5f) atomicAdd(&h[(__float_as_uint(v.y) >> 11) & 4095u], 1u);
        if (v.z > 0.5f) atomicAdd(&h[(__float_as_uint(v.z) >> 11) & 4095u], 1u);
        if (v.w > 0.5f) atomicAdd(&h[(__float_as_uint(v.w) >> 11) & 4095u], 1u);
    }
    __syncthreads();
    unsigned* dst = phist + ((size_t)(b * HBLK + g) << 12);
    for (int k = threadIdx.x; k < 4096; k += 256) dst[k] = h[k];   // pure store
}

// ------- Kernel 2: sum partials, suffix-scan -> starts/cut/P/M; zero ctrs ----
__global__ __launch_bounds__(64) void k_cut(const unsigned* __restrict__ phist,
                                            unsigned* __restrict__ start,
                                            unsigned* __restrict__ meta,
                                            unsigned* __restrict__ ecnt,
                                            unsigned* __restrict__ bcnt,
                                            unsigned* __restrict__ dcnt) {
    const int b = blockIdx.x;
    const int lane = threadIdx.x;
    const int base = b * 4096 + lane * 64;
    ecnt[b * 64 + lane] = 0u;
    if (lane == 0) dcnt[b] = 0u;
#pragma unroll
    for (int k = 0; k < 64; ++k) bcnt[base + k] = 0u;
    unsigned v[64];
#pragma unroll
    for (int k = 0; k < 64; ++k) v[k] = 0u;
    for (int g = 0; g < HBLK; ++g) {
        const unsigned* src = phist + ((size_t)(b * HBLK + g) << 12) + lane * 64;
#pragma unroll
        for (int k = 0; k < 64; ++k) v[k] += src[k];
    }
#pragma unroll
    for (int k = 62; k >= 0; --k) v[k] += v[k + 1];
    unsigned tot = v[0];
    unsigned incl = tot;
#pragma unroll
    for (int d = 1; d < 64; d <<= 1) {
        unsigned t = __shfl_down(incl, d);
        if (lane + d < 64) incl += t;
    }
    unsigned sfx_above = incl - tot;          // sum over lanes > lane
    unsigned total = __shfl(incl, 0);
#pragma unroll
    for (int k = 0; k < 63; ++k) start[base + k] = v[k + 1] + sfx_above;
    start[base + 63] = sfx_above;
    if (lane == 0) {
        unsigned P = total < KEYCAP ? total : KEYCAP;
        meta[b] = 0u;
        meta[8 + b] = P;
        meta[16 + b] = P < KPRE ? P : KPRE;
    }
#pragma unroll
    for (int k = 0; k < 64; ++k) {
        unsigned sfxk = v[k] + sfx_above;
        unsigned nxt = (k < 63) ? (v[k + 1] + sfx_above) : sfx_above;
        if (sfxk >= (unsigned)KPRE && nxt < (unsigned)KPRE) {
            unsigned P = sfxk < KEYCAP ? sfxk : KEYCAP;
            meta[b] = (unsigned)(lane * 64 + k);
            meta[8 + b] = P;
            meta[16 + b] = (unsigned)KPRE;
        }
    }
}

// ---- Kernel 3: key scatter + device-barrier + PARALLEL rank&decode ----------
__global__ __launch_bounds__(256) void k_collect(const float* __restrict__ score,
                                                 const unsigned* __restrict__ meta,
                                                 const unsigned* __restrict__ start,
                                                 unsigned* __restrict__ bcnt,
                                                 u64* __restrict__ keys,
                                                 const float* __restrict__ delta,
                                                 const float* __restrict__ anchors,
                                                 float* __restrict__ cand,
                                                 unsigned* __restrict__ dcnt) {
#pragma clang fp contract(off)
    const int b = blockIdx.y;
    const int tid = threadIdx.x;
    const unsigned cut = meta[b];
    const float4* s4 = (const float4*)(score + (size_t)b * NANCH);
    int q0 = blockIdx.x * 256 + tid;
    const int stride = CBLK * 256;
    for (int q = q0; q < NANCH / 4; q += stride) {
        float4 v = s4[q];
        const int ib = q << 2;
#define TRY(COMP, OFF)                                                        \
        if (v.COMP > 0.5f) {                                                  \
            unsigned bits = __float_as_uint(v.COMP);                          \
            unsigned bucket = (bits >> 11) & 4095u;                           \
            if (bucket >= cut) {                                              \
                unsigned pos = start[b * 4096 + bucket] +                     \
                               atomicAdd(&bcnt[b * 4096 + bucket], 1u);       \
                if (pos < (unsigned)KEYCAP)                                   \
                    keys[(size_t)b * KEYCAP + pos] =                          \
                        ((u64)bits << 32) | (unsigned)(~(unsigned)(ib + OFF));\
            }                                                                 \
        }
        TRY(x, 0) TRY(y, 1) TRY(z, 2) TRY(w, 3)
#undef TRY
    }

    // ---- device-scope barrier across this batch's CBLK blocks --------------
    __threadfence();                       // release: key stores visible
    __syncthreads();
    if (tid == 0) {
        __hip_atomic_fetch_add(&dcnt[b], 1u, __ATOMIC_ACQ_REL, __HIP_MEMORY_SCOPE_AGENT);
        while (__hip_atomic_load(&dcnt[b], __ATOMIC_ACQUIRE, __HIP_MEMORY_SCOPE_AGENT)
               < (unsigned)CBLK) { __builtin_amdgcn_s_sleep(1); }
    }
    __syncthreads();                       // all threads see barrier passed

    // ---- rank within bucket + decode (all blocks participate) --------------
    const int P = (int)meta[8 + b];
    const int M = (int)meta[16 + b];
    const u64* kb = keys + (size_t)b * KEYCAP;
    const int s = blockIdx.x * 256 + tid;  // 8192 threads >= KEYCAP
    if (s >= KEYCAP) return;
    if (s >= M && s < KPRE) {
        float4* c4 = (float4*)(cand + (size_t)b * KPRE * 4);
        c4[s] = make_float4(0.f, 0.f, 0.f, 0.f);
    }
    if (s >= P) return;
    u64 key = kb[s];
    unsigned bucket = (unsigned)(key >> 43) & 4095u;
    int base = (int)start[b * 4096 + bucket];
    int end = (bucket > 0) ? (int)start[b * 4096 + bucket - 1] : P;
    if (end > P) end = P;
    int rank = 0;
    for (int t = base; t < end; ++t) rank += (kb[t] > key) ? 1 : 0;
    int pos = base + rank;
    if (pos >= KPRE) return;
    int n = (int)(~(unsigned)(key & 0xFFFFFFFFull));
    float4 t4 = *(const float4*)(delta + ((size_t)b * NANCH + n) * 4);
    float4 a4 = *(const float4*)(anchors + (size_t)n * 4);
    float xa = (a4.x + a4.y) * 0.5f;
    float ya = (a4.z + a4.w) * 0.5f;
    float wa = a4.y - a4.x;
    float ha = a4.w - a4.z;
    float x = t4.x * wa + xa;
    float y = t4.y * ha + ya;
    float w = expf(t4.z) * wa;
    float h = expf(t4.w) * ha;
    float xmn = fminf(fmaxf(x - w * 0.5f, 0.f), 1.f);
    float xmx = fminf(fmaxf(x + w * 0.5f, 0.f), 1.f);
    float ymn = fminf(fmaxf(y - h * 0.5f, 0.f), 1.f);
    float ymx = fminf(fmaxf(y + h * 0.5f, 0.f), 1.f);
    float* o = cand + ((size_t)b * KPRE + pos) * 4;
    o[0] = xmn; o[1] = xmx; o[2] = ymn; o[3] = ymx;
}

// ===== Kernel 4: sparse edge extraction — split i-halves for 2x waves ========
__global__ __launch_bounds__(256) void k_geo(const float* __restrict__ cand,
                                             unsigned* __restrict__ ecnt,
                                             unsigned* __restrict__ ebuf) {
#pragma clang fp contract(off)
    const int b = blockIdx.y;
    const int h = blockIdx.z;             // i-half: rows [h*32, h*32+32)
    const int lane = threadIdx.x & 63;
    const int wv = threadIdx.x >> 6;
    int t = (blockIdx.x << 2) + wv;       // in [0, GTASKS)
    int c = 0;
    while (true) { int n = (NWORDS - c + 3) >> 2; if (t < n) break; t -= n; ++c; }
    const int wbase = c + (t << 2);
    const bool nd0 = (wbase != c);        // slot 0 diagonal iff wbase == c

    const float4* c4 = (const float4*)(cand + (size_t)b * KPRE * 4);
    const int iq0 = c << 6;
    const int il = iq0 + lane;
    float4 bi_l;
    float ai_l;
    if (il < KPRE) {
        bi_l = c4[il];
        ai_l = (bi_l.y - bi_l.x) * (bi_l.w - bi_l.z);
    } else {
        bi_l = make_float4(2.f, -1.f, 2.f, -1.f);
        ai_l = 0.f;
    }
    float ai69_l = 0.69f * ai_l;

    unsigned* cl = &ecnt[b * 64 + c];                       // per-(b,c) counter
    unsigned* bb = ebuf + ((size_t)(b * 64 + c)) * EB_CAP;  // per-(b,c) bucket

    float4 bq0, bq1, bq2, bq3;
    float aq0, aq1, aq2, aq3, aq69_0, aq69_1, aq69_2, aq69_3;
#define LOADQ(S)                                                              \
    { int w_ = wbase + S; int jq_ = (w_ << 6) + lane;                         \
      if (w_ < NWORDS && jq_ < KPRE) {                                        \
          bq##S = c4[jq_];                                                    \
          aq##S = (bq##S.y - bq##S.x) * (bq##S.w - bq##S.z);                  \
      } else { bq##S = make_float4(2.f, -1.f, 2.f, -1.f); aq##S = 0.f; }      \
      aq69_##S = 0.69f * aq##S; }
    LOADQ(0) LOADQ(1) LOADQ(2) LOADQ(3)
#undef LOADQ

#pragma unroll 4
    for (int ii = 0; ii < 32; ++ii) {
        const int i = (h << 5) | ii;
        float bix = readlane_f(bi_l.x, i);
        float biy = readlane_f(bi_l.y, i);
        float biz = readlane_f(bi_l.z, i);
        float biw = readlane_f(bi_l.w, i);
        float ai69 = readlane_f(ai69_l, i);
        bool ok0, ok1, ok2, ok3;
        float in0, in1, in2, in3;
#define PAIR(S, OKV, INV)                                                     \
        { float iw = fminf(biy, bq##S.y) - fmaxf(bix, bq##S.x);               \
          float ih = fminf(biw, bq##S.w) - fmaxf(biz, bq##S.z);               \
          iw = fmaxf(iw, 0.0f); ih = fmaxf(ih, 0.0f);                         \
          INV = iw * ih;                                                      \
          OKV = INV > fmaxf(ai69, aq69_##S); }
        PAIR(0, ok0, in0) PAIR(1, ok1, in1) PAIR(2, ok2, in2) PAIR(3, ok3, in3)
#undef PAIR
        ok0 = ok0 && (nd0 || lane > i);
        if (__any(ok0 | ok1 | ok2 | ok3)) {
            float ai = readlane_f(ai_l, i);
            u64 wd0 = 0, wd1 = 0, wd2 = 0, wd3 = 0;
#define HITS(S, OKV, INV, WD)                                                 \
            if (__any(OKV)) {                                                 \
                float uni = ai + aq##S - INV;                                 \
                WD = __ballot(OKV && (INV / fmaxf(uni, 1e-8f) > 0.7f));       \
            }
            HITS(0, ok0, in0, wd0) HITS(1, ok1, in1, wd1)
            HITS(2, ok2, in2, wd2) HITS(3, ok3, in3, wd3)
#undef HITS
            if (lane == 0) {
                int pc = __builtin_popcountll(wd0) + __builtin_popcountll(wd1) +
                         __builtin_popcountll(wd2) + __builtin_popcountll(wd3);
                if (pc) {
                    unsigned slot = atomicAdd(cl, (unsigned)pc);
                    unsigned ibase = (unsigned)(iq0 + i) << 12;
#define WR(S, WD)                                                             \
                    { u64 w_ = WD; unsigned jb = (unsigned)((wbase + S) << 6);\
                      while (w_) { int jj = __builtin_ctzll(w_);              \
                          w_ &= w_ - 1;                                       \
                          if (slot < (unsigned)EB_CAP)                        \
                              bb[slot] = ibase | (jb + (unsigned)jj);         \
                          ++slot; } }
                    WR(0, wd0) WR(1, wd1) WR(2, wd2) WR(3, wd3)
#undef WR
                }
            }
        }
    }
}

// ===== Kernel 5: greedy NMS — parallel compaction + flat-LDS Jacobi ==========
__global__ __launch_bounds__(256) void k_nms(const float* __restrict__ cand,
                                             const unsigned* __restrict__ ecnt,
                                             const unsigned* __restrict__ ebuf,
                                             const unsigned* __restrict__ meta,
                                             float* __restrict__ out) {
#pragma clang fp contract(off)
    const int b = blockIdx.x;
    const int tid = threadIdx.x;
    const int lane = tid & 63;
    const int wv = tid >> 6;
    const int M = (int)meta[16 + b];
    const int nchunks = (M + 63) >> 6;

    __shared__ u64 accS[64];
    __shared__ u64 supS[64];
    __shared__ unsigned offS[65];
    __shared__ unsigned eflat[ELTOT];   // 32 KB flat edge list (absolute i,j)
    __shared__ int sel[MAXOUT];         // 8 KB
    __shared__ float4 bxF[KPRE];        // 64 KB (fallback only)
    __shared__ float sarF[KPRE];        // 16 KB (fallback only)
    __shared__ int s_cnt, s_fb, s_changed;

    if (tid == 0) { s_cnt = 0; s_fb = 0; }
    __syncthreads();
    if (wv == 0) {
        unsigned n = ecnt[b * 64 + lane];
        if (n > (unsigned)EB_CAP) atomicOr(&s_fb, 1);
        unsigned scan = n;
#pragma unroll
        for (int d = 1; d < 64; d <<= 1) {
            unsigned t = __shfl_up(scan, d);
            if (lane >= d) scan += t;
        }
        offS[lane + 1] = scan;
        if (lane == 0) offS[0] = 0u;
        if (lane == 63 && scan > (unsigned)ELTOT) atomicOr(&s_fb, 1);
    }
    if (tid < 64) {
        int lo = tid << 6;
        u64 vmask = 0ull;
        if (lo < M) {
            int nr = M - lo;
            vmask = (nr >= 64) ? ~0ull : ((1ull << nr) - 1ull);
        }
        accS[tid] = vmask;
    }
    __syncthreads();
    const bool fb = s_fb != 0;
    const unsigned E = offS[64];

    if (!fb) {
        // ---- parallel compaction: 64 buckets -> flat LDS (4 threads/bucket)
        {
            const int c = tid & 63;
            const int sub = tid >> 6;
            const unsigned o0 = offS[c];
            const unsigned n = offS[c + 1] - o0;
            const unsigned* bb = ebuf + ((size_t)(b * 64 + c)) * EB_CAP;
            for (unsigned e = (unsigned)sub; e < n; e += 4u)
                eflat[o0 + e] = bb[e];
        }
        __syncthreads();

        // ---- Jacobi iteration to the greedy fixpoint (flat list, LDS-only) --
        for (int pass = 0; pass < 8192; ++pass) {
            if (tid < 64) supS[tid] = 0ull;
            if (tid == 0) s_changed = 0;
            __syncthreads();
            for (unsigned e = (unsigned)tid; e < E; e += 256u) {
                unsigned ed = eflat[e];
                unsigned i = ed >> 12;
                unsigned j = ed & 4095u;
                if ((accS[i >> 6] >> (i & 63)) & 1ull)
                    atomicOr((unsigned*)&supS[j >> 6] + ((j >> 5) & 1u),
                             1u << (j & 31u));
            }
            __syncthreads();
            if (tid < 64) {
                int lo = tid << 6;
                u64 vmask = 0ull;
                if (lo < M) {
                    int nr = M - lo;
                    vmask = (nr >= 64) ? ~0ull : ((1ull << nr) - 1ull);
                }
                u64 na = vmask & ~supS[tid];
                if (na != accS[tid]) { accS[tid] = na; s_changed = 1; }
            }
            __syncthreads();
            if (s_changed == 0) break;
        }

        // ---- truncate to first MAXOUT accepts, expand to sel ----------------
        if (wv == 0) {
            u64 aw = accS[lane];
            int pc = __builtin_popcountll(aw);
            int scan = pc;
#pragma unroll
            for (int d = 1; d < 64; d <<= 1) {
                int t = __shfl_up(scan, d);
                if (lane >= d) scan += t;
            }
            int pos = scan - pc;                    // exclusive prefix
            int total = __shfl(scan, 63);
            int cnt = total < MAXOUT ? total : MAXOUT;
            int kept = MAXOUT - pos;
            kept = kept < 0 ? 0 : (kept > pc ? pc : kept);
            for (int t = 0; t < pc - kept; ++t)     // drop highest-index bits
                aw &= ~(0x8000000000000000ull >> __builtin_clzll(aw));
            while (aw) {
                int r = __builtin_ctzll(aw);
                aw &= aw - 1;
                sel[pos++] = (lane << 6) + r;
            }
            if (lane == 0) s_cnt = cnt;
        }
    } else {
        // ---------- fallback: exact serial recompute (overflow-safe) --------
        const float4* c4 = (const float4*)(cand + (size_t)b * KPRE * 4);
        for (int k = tid; k < KPRE; k += 256) {
            float4 v = c4[k];
            bxF[k] = v;
            sarF[k] = (v.y - v.x) * (v.w - v.z);
        }
        __syncthreads();
        if (wv == 0) {
            auto iougt = [&](float4 A, float aA, float4 Bq, float aB) -> bool {
#pragma clang fp contract(off)
                float iw = fminf(A.y, Bq.y) - fmaxf(A.x, Bq.x);
                iw = fmaxf(iw, 0.0f);
                float ih = fminf(A.w, Bq.w) - fmaxf(A.z, Bq.z);
                ih = fmaxf(ih, 0.0f);
                float inter = iw * ih;
                float uni = aA + aB - inter;
                return inter / fmaxf(uni, 1e-8f) > 0.7f;
            };
            u64 accReg = 0ull;
            int cnt = 0;
            for (int c = 0; c < nchunks && cnt < MAXOUT; ++c) {
                int r = (c << 6) + lane;
                bool valid = r < M;
                float4 bq = valid ? bxF[r] : make_float4(0.f, 0.f, 0.f, 0.f);
                float aq = valid ? sarF[r] : 0.f;
                u64 inT = 0ull;
                for (int i2 = 0; i2 < 64; ++i2) {
                    if (valid && i2 < lane) {
                        int ri = (c << 6) + i2;
                        if (iougt(bxF[ri], sarF[ri], bq, aq)) inT |= 1ull << i2;
                    }
                }
                bool supb = false;
                for (int cc = 0; cc < c; ++cc) {
                    u64 aw = readlane64(accReg, cc);
                    while (aw) {
                        int rb = __builtin_ctzll(aw);
                        aw &= aw - 1;
                        int ia = (cc << 6) + rb;
                        if (valid && iougt(bxF[ia], sarF[ia], bq, aq)) supb = true;
                    }
                }
                u64 live = __ballot(valid && !supb);
                u64 am = 0ull;
                while (live) {
                    u64 pred = __ballot((inT & live) != 0ull);
                    u64 acc = live & ~pred;
                    u64 sup = __ballot((inT & acc) != 0ull);
                    am |= acc;
                    live &= ~(acc | sup);
                }
                int pc = __builtin_popcountll(am);
                if (cnt + pc >= MAXOUT) {
                    int drop = cnt + pc - MAXOUT;
                    for (int t = 0; t < drop; ++t)
                        am &= ~(0x8000000000000000ull >> __builtin_clzll(am));
                    pc = MAXOUT - cnt;
                }
                if (lane == 0) {
                    u64 tmp = am;
                    int p = cnt;
                    while (tmp) {
                        int rr = __builtin_ctzll(tmp);
                        tmp &= tmp - 1;
                        sel[p++] = (c << 6) + rr;
                    }
                }
                if (lane == c) accReg |= am;
                cnt += pc;
            }
            if (lane == 0) s_cnt = cnt;
        }
    }
    __syncthreads();

    const int cntF = s_cnt;
    const float4* c4o = (const float4*)(cand + (size_t)b * KPRE * 4);
    float4* o4 = (float4*)(out + (size_t)b * MAXOUT * 4);
    for (int r = tid; r < MAXOUT; r += 256) {
        float4 v = make_float4(0.0f, 0.0f, 0.0f, 0.0f);
        if (r < cntF) v = c4o[sel[r]];
        o4[r] = v;
    }
}

// ---------------- launch ------------------------------------------------------
extern "C" void kernel_launch(void* const* d_in, const int* in_sizes, int n_in,
                              void* d_out, int out_size, void* d_ws, size_t ws_size,
                              hipStream_t stream) {
    const float* score   = (const float*)d_in[0];
    const float* delta   = (const float*)d_in[1];
    const float* anchors = (const float*)d_in[2];
    float* out = (float*)d_out;

    uint8_t* w8 = (uint8_t*)d_ws;
    unsigned* phist = (unsigned*)(w8 + 0);        // 8 x 8 x 4096 u32 (1 MB, pure writes)
    unsigned* start = (unsigned*)(w8 + 1048576);  // 8 x 4096 u32
    unsigned* bcnt  = (unsigned*)(w8 + 1179648);  // 8 x 4096 u32 (zeroed by k_cut)
    unsigned* meta  = (unsigned*)(w8 + 1310720);  // cut[8] | P[8] | M[8]
    unsigned* ecnt  = (unsigned*)(w8 + 1310848);  // 8 x 64 u32 (zeroed by k_cut)
    unsigned* dcnt  = (unsigned*)(w8 + 1312896);  // 8 u32 (zeroed by k_cut)
    u64* keys       = (u64*)(w8 + 1312928);       // 8 x 4224 u64
    float* cand     = (float*)(w8 + 1583264);     // 8 x 4000 x 4 f32
    unsigned* ebuf  = (unsigned*)(w8 + 2095264);  // 8 x 64 x 2048 u32 (4 MB)

    k_hist<<<dim3(HBLK, NB), 256, 0, stream>>>(score, phist);
    k_cut<<<NB, 64, 0, stream>>>(phist, start, meta, ecnt, bcnt, dcnt);
    k_collect<<<dim3(CBLK, NB), 256, 0, stream>>>(score, meta, start, bcnt, keys,
                                                  delta, anchors, cand, dcnt);
    k_geo<<<dim3(GTASKS / 4, NB, 2), 256, 0, stream>>>(cand, ecnt, ebuf);
    k_nms<<<NB, 256, 0, stream>>>(cand, ecnt, ebuf, meta, out);
}

// Round 23
// 84.921 us; speedup vs baseline: 1.4762x; 1.4762x over previous
//
#include <hip/hip_runtime.h>
#include <stdint.h>

#define NB 8
#define NH 96
#define NW_ 96
#define NA 9
#define NANCH (NH * NW_ * NA)   // 82944
#define KPRE 4000
#define MAXOUT 2000
#define KEYCAP 4224             // >= KPRE + max expected cut-bucket size
#define NWORDS 63               // ceil(4000/64)
#define GTASKS 528              // per batch: sum_c ceil((63-c)/4)
#define EB_CAP 2048             // edges per (batch, i-chunk) bucket (global)
#define ELTOT 8192              // flat edge capacity per batch (32 KB LDS)
#define HBLK 8                  // histogram blocks per batch

typedef unsigned long long u64;

__device__ __forceinline__ u64 readlane64(u64 v, int l) {
    unsigned lo = (unsigned)__builtin_amdgcn_readlane((int)(unsigned)v, l);
    unsigned hi = (unsigned)__builtin_amdgcn_readlane((int)(unsigned)(v >> 32), l);
    return ((u64)hi << 32) | lo;
}
__device__ __forceinline__ float readlane_f(float v, int l) {
    return __uint_as_float((unsigned)__builtin_amdgcn_readlane((int)__float_as_uint(v), l));
}

// ------- Kernel 1: per-block partial histograms (pure stores, no memset) -----
__global__ __launch_bounds__(256) void k_hist(const float* __restrict__ score,
                                              unsigned* __restrict__ phist) {
    const int b = blockIdx.y;
    const int g = blockIdx.x;
    __shared__ unsigned h[4096];
    for (int i = threadIdx.x; i < 4096; i += 256) h[i] = 0u;
    __syncthreads();
    const float4* s4 = (const float4*)(score + (size_t)b * NANCH);
    int i0 = g * 256 + threadIdx.x;
    const int stride = HBLK * 256;
    for (int i = i0; i < NANCH / 4; i += stride) {
        float4 v = s4[i];
        if (v.x > 0.5f) atomicAdd(&h[(__float_as_uint(v.x) >> 11) & 4095u], 1u);
        if (v.y > 0.5f) atomicAdd(&h[(__float_as_uint(v.y) >> 11) & 4095u], 1u);
        if (v.z > 0.5f) atomicAdd(&h[(__float_as_uint(v.z) >> 11) & 4095u], 1u);
        if (v.w > 0.5f) atomicAdd(&h[(__float_as_uint(v.w) >> 11) & 4095u], 1u);
    }
    __syncthreads();
    unsigned* dst = phist + ((size_t)(b * HBLK + g) << 12);
    for (int k = threadIdx.x; k < 4096; k += 256) dst[k] = h[k];   // pure store
}

// ------- Kernel 2: sum partials, suffix-scan -> starts/cut/P/M; zero ctrs ----
__global__ __launch_bounds__(64) void k_cut(const unsigned* __restrict__ phist,
                                            unsigned* __restrict__ start,
                                            unsigned* __restrict__ meta,
                                            unsigned* __restrict__ ecnt,
                                            unsigned* __restrict__ bcnt) {
    const int b = blockIdx.x;
    const int lane = threadIdx.x;
    const int base = b * 4096 + lane * 64;
    ecnt[b * 64 + lane] = 0u;
#pragma unroll
    for (int k = 0; k < 64; ++k) bcnt[base + k] = 0u;
    unsigned v[64];
#pragma unroll
    for (int k = 0; k < 64; ++k) v[k] = 0u;
    for (int g = 0; g < HBLK; ++g) {
        const unsigned* src = phist + ((size_t)(b * HBLK + g) << 12) + lane * 64;
#pragma unroll
        for (int k = 0; k < 64; ++k) v[k] += src[k];
    }
#pragma unroll
    for (int k = 62; k >= 0; --k) v[k] += v[k + 1];
    unsigned tot = v[0];
    unsigned incl = tot;
#pragma unroll
    for (int d = 1; d < 64; d <<= 1) {
        unsigned t = __shfl_down(incl, d);
        if (lane + d < 64) incl += t;
    }
    unsigned sfx_above = incl - tot;          // sum over lanes > lane
    unsigned total = __shfl(incl, 0);
#pragma unroll
    for (int k = 0; k < 63; ++k) start[base + k] = v[k + 1] + sfx_above;
    start[base + 63] = sfx_above;
    if (lane == 0) {
        unsigned P = total < KEYCAP ? total : KEYCAP;
        meta[b] = 0u;
        meta[8 + b] = P;
        meta[16 + b] = P < KPRE ? P : KPRE;
    }
#pragma unroll
    for (int k = 0; k < 64; ++k) {
        unsigned sfxk = v[k] + sfx_above;
        unsigned nxt = (k < 63) ? (v[k + 1] + sfx_above) : sfx_above;
        if (sfxk >= (unsigned)KPRE && nxt < (unsigned)KPRE) {
            unsigned P = sfxk < KEYCAP ? sfxk : KEYCAP;
            meta[b] = (unsigned)(lane * 64 + k);
            meta[8 + b] = P;
            meta[16 + b] = (unsigned)KPRE;
        }
    }
}

// ------- Kernel 3: bucketed scatter of candidate keys (float4 loads) ---------
__global__ __launch_bounds__(256) void k_collect(const float* __restrict__ score,
                                                 const unsigned* __restrict__ meta,
                                                 const unsigned* __restrict__ start,
                                                 unsigned* __restrict__ bcnt,
                                                 u64* __restrict__ keys) {
    const int b = blockIdx.y;
    const unsigned cut = meta[b];
    const float4* s4 = (const float4*)(score + (size_t)b * NANCH);
    int q0 = blockIdx.x * 256 + threadIdx.x;
    const int stride = 32 * 256;
    for (int q = q0; q < NANCH / 4; q += stride) {
        float4 v = s4[q];
        const int ib = q << 2;
#define TRY(COMP, OFF)                                                        \
        if (v.COMP > 0.5f) {                                                  \
            unsigned bits = __float_as_uint(v.COMP);                          \
            unsigned bucket = (bits >> 11) & 4095u;                           \
            if (bucket >= cut) {                                              \
                unsigned pos = start[b * 4096 + bucket] +                     \
                               atomicAdd(&bcnt[b * 4096 + bucket], 1u);       \
                if (pos < (unsigned)KEYCAP)                                   \
                    keys[(size_t)b * KEYCAP + pos] =                          \
                        ((u64)bits << 32) | (unsigned)(~(unsigned)(ib + OFF));\
            }                                                                 \
        }
        TRY(x, 0) TRY(y, 1) TRY(z, 2) TRY(w, 3)
#undef TRY
    }
}

// -------- Kernel 4: rank within bucket (exact sort position) + decode --------
__global__ void k_rank_decode(const u64* __restrict__ keys,
                              const unsigned* __restrict__ start,
                              const unsigned* __restrict__ meta,
                              const float* __restrict__ delta,
                              const float* __restrict__ anchors,
                              float* __restrict__ cand) {
#pragma clang fp contract(off)
    const int b = blockIdx.y;
    const int s = blockIdx.x * blockDim.x + threadIdx.x;
    const int P = (int)meta[8 + b];
    const int M = (int)meta[16 + b];
    if (s >= M && s < KPRE) {
        float4* c4 = (float4*)(cand + (size_t)b * KPRE * 4);
        c4[s] = make_float4(0.f, 0.f, 0.f, 0.f);
    }
    if (s >= P) return;
    const u64* kb = keys + (size_t)b * KEYCAP;
    u64 key = kb[s];
    unsigned bucket = (unsigned)(key >> 43) & 4095u;
    int base = (int)start[b * 4096 + bucket];
    int end = (bucket > 0) ? (int)start[b * 4096 + bucket - 1] : P;
    if (end > P) end = P;
    int rank = 0;
    for (int t = base; t < end; ++t) rank += (kb[t] > key) ? 1 : 0;
    int pos = base + rank;
    if (pos >= KPRE) return;
    int n = (int)(~(unsigned)(key & 0xFFFFFFFFull));
    float4 t4 = *(const float4*)(delta + ((size_t)b * NANCH + n) * 4);
    float4 a4 = *(const float4*)(anchors + (size_t)n * 4);
    float xa = (a4.x + a4.y) * 0.5f;
    float ya = (a4.z + a4.w) * 0.5f;
    float wa = a4.y - a4.x;
    float ha = a4.w - a4.z;
    float x = t4.x * wa + xa;
    float y = t4.y * ha + ya;
    float w = expf(t4.z) * wa;
    float h = expf(t4.w) * ha;
    float xmn = fminf(fmaxf(x - w * 0.5f, 0.f), 1.f);
    float xmx = fminf(fmaxf(x + w * 0.5f, 0.f), 1.f);
    float ymn = fminf(fmaxf(y - h * 0.5f, 0.f), 1.f);
    float ymx = fminf(fmaxf(y + h * 0.5f, 0.f), 1.f);
    float* o = cand + ((size_t)b * KPRE + pos) * 4;
    o[0] = xmn; o[1] = xmx; o[2] = ymn; o[3] = ymx;
}

// ===== Kernel 5: sparse edge extraction — split i-halves for 2x waves ========
__global__ __launch_bounds__(256) void k_geo(const float* __restrict__ cand,
                                             unsigned* __restrict__ ecnt,
                                             unsigned* __restrict__ ebuf) {
#pragma clang fp contract(off)
    const int b = blockIdx.y;
    const int h = blockIdx.z;             // i-half: rows [h*32, h*32+32)
    const int lane = threadIdx.x & 63;
    const int wv = threadIdx.x >> 6;
    int t = (blockIdx.x << 2) + wv;       // in [0, GTASKS)
    int c = 0;
    while (true) { int n = (NWORDS - c + 3) >> 2; if (t < n) break; t -= n; ++c; }
    const int wbase = c + (t << 2);
    const bool nd0 = (wbase != c);        // slot 0 diagonal iff wbase == c

    const float4* c4 = (const float4*)(cand + (size_t)b * KPRE * 4);
    const int iq0 = c << 6;
    const int il = iq0 + lane;
    float4 bi_l;
    float ai_l;
    if (il < KPRE) {
        bi_l = c4[il];
        ai_l = (bi_l.y - bi_l.x) * (bi_l.w - bi_l.z);
    } else {
        bi_l = make_float4(2.f, -1.f, 2.f, -1.f);
        ai_l = 0.f;
    }
    float ai69_l = 0.69f * ai_l;

    unsigned* cl = &ecnt[b * 64 + c];                       // per-(b,c) counter
    unsigned* bb = ebuf + ((size_t)(b * 64 + c)) * EB_CAP;  // per-(b,c) bucket

    float4 bq0, bq1, bq2, bq3;
    float aq0, aq1, aq2, aq3, aq69_0, aq69_1, aq69_2, aq69_3;
#define LOADQ(S)                                                              \
    { int w_ = wbase + S; int jq_ = (w_ << 6) + lane;                         \
      if (w_ < NWORDS && jq_ < KPRE) {                                        \
          bq##S = c4[jq_];                                                    \
          aq##S = (bq##S.y - bq##S.x) * (bq##S.w - bq##S.z);                  \
      } else { bq##S = make_float4(2.f, -1.f, 2.f, -1.f); aq##S = 0.f; }      \
      aq69_##S = 0.69f * aq##S; }
    LOADQ(0) LOADQ(1) LOADQ(2) LOADQ(3)
#undef LOADQ

#pragma unroll 4
    for (int ii = 0; ii < 32; ++ii) {
        const int i = (h << 5) | ii;
        float bix = readlane_f(bi_l.x, i);
        float biy = readlane_f(bi_l.y, i);
        float biz = readlane_f(bi_l.z, i);
        float biw = readlane_f(bi_l.w, i);
        float ai69 = readlane_f(ai69_l, i);
        bool ok0, ok1, ok2, ok3;
        float in0, in1, in2, in3;
#define PAIR(S, OKV, INV)                                                     \
        { float iw = fminf(biy, bq##S.y) - fmaxf(bix, bq##S.x);               \
          float ih = fminf(biw, bq##S.w) - fmaxf(biz, bq##S.z);               \
          iw = fmaxf(iw, 0.0f); ih = fmaxf(ih, 0.0f);                         \
          INV = iw * ih;                                                      \
          OKV = INV > fmaxf(ai69, aq69_##S); }
        PAIR(0, ok0, in0) PAIR(1, ok1, in1) PAIR(2, ok2, in2) PAIR(3, ok3, in3)
#undef PAIR
        ok0 = ok0 && (nd0 || lane > i);
        if (__any(ok0 | ok1 | ok2 | ok3)) {
            float ai = readlane_f(ai_l, i);
            u64 wd0 = 0, wd1 = 0, wd2 = 0, wd3 = 0;
#define HITS(S, OKV, INV, WD)                                                 \
            if (__any(OKV)) {                                                 \
                float uni = ai + aq##S - INV;                                 \
                WD = __ballot(OKV && (INV / fmaxf(uni, 1e-8f) > 0.7f));       \
            }
            HITS(0, ok0, in0, wd0) HITS(1, ok1, in1, wd1)
            HITS(2, ok2, in2, wd2) HITS(3, ok3, in3, wd3)
#undef HITS
            if (lane == 0) {
                int pc = __builtin_popcountll(wd0) + __builtin_popcountll(wd1) +
                         __builtin_popcountll(wd2) + __builtin_popcountll(wd3);
                if (pc) {
                    unsigned slot = atomicAdd(cl, (unsigned)pc);
                    unsigned ibase = (unsigned)(iq0 + i) << 12;
#define WR(S, WD)                                                             \
                    { u64 w_ = WD; unsigned jb = (unsigned)((wbase + S) << 6);\
                      while (w_) { int jj = __builtin_ctzll(w_);              \
                          w_ &= w_ - 1;                                       \
                          if (slot < (unsigned)EB_CAP)                        \
                              bb[slot] = ibase | (jb + (unsigned)jj);         \
                          ++slot; } }
                    WR(0, wd0) WR(1, wd1) WR(2, wd2) WR(3, wd3)
#undef WR
                }
            }
        }
    }
}

// ===== Kernel 6: greedy NMS — parallel compaction + flat-LDS Jacobi ==========
__global__ __launch_bounds__(256) void k_nms(const float* __restrict__ cand,
                                             const unsigned* __restrict__ ecnt,
                                             const unsigned* __restrict__ ebuf,
                                             const unsigned* __restrict__ meta,
                                             float* __restrict__ out) {
#pragma clang fp contract(off)
    const int b = blockIdx.x;
    const int tid = threadIdx.x;
    const int lane = tid & 63;
    const int wv = tid >> 6;
    const int M = (int)meta[16 + b];
    const int nchunks = (M + 63) >> 6;

    __shared__ u64 accS[64];
    __shared__ u64 supS[64];
    __shared__ unsigned offS[65];
    __shared__ unsigned eflat[ELTOT];   // 32 KB flat edge list (absolute i,j)
    __shared__ int sel[MAXOUT];         // 8 KB
    __shared__ float4 bxF[KPRE];        // 64 KB (fallback only)
    __shared__ float sarF[KPRE];        // 16 KB (fallback only)
    __shared__ int s_cnt, s_fb, s_changed;

    if (tid == 0) { s_cnt = 0; s_fb = 0; }
    __syncthreads();
    if (wv == 0) {
        unsigned n = ecnt[b * 64 + lane];
        if (n > (unsigned)EB_CAP) atomicOr(&s_fb, 1);
        unsigned scan = n;
#pragma unroll
        for (int d = 1; d < 64; d <<= 1) {
            unsigned t = __shfl_up(scan, d);
            if (lane >= d) scan += t;
        }
        offS[lane + 1] = scan;
        if (lane == 0) offS[0] = 0u;
        if (lane == 63 && scan > (unsigned)ELTOT) atomicOr(&s_fb, 1);
    }
    if (tid < 64) {
        int lo = tid << 6;
        u64 vmask = 0ull;
        if (lo < M) {
            int nr = M - lo;
            vmask = (nr >= 64) ? ~0ull : ((1ull << nr) - 1ull);
        }
        accS[tid] = vmask;
    }
    __syncthreads();
    const bool fb = s_fb != 0;
    const unsigned E = offS[64];

    if (!fb) {
        // ---- parallel compaction: 64 buckets -> flat LDS (4 threads/bucket)
        {
            const int c = tid & 63;
            const int sub = tid >> 6;
            const unsigned o0 = offS[c];
            const unsigned n = offS[c + 1] - o0;
            const unsigned* bb = ebuf + ((size_t)(b * 64 + c)) * EB_CAP;
            for (unsigned e = (unsigned)sub; e < n; e += 4u)
                eflat[o0 + e] = bb[e];
        }
        __syncthreads();

        // ---- Jacobi iteration to the greedy fixpoint (flat list, LDS-only) --
        for (int pass = 0; pass < 8192; ++pass) {
            if (tid < 64) supS[tid] = 0ull;
            if (tid == 0) s_changed = 0;
            __syncthreads();
            for (unsigned e = (unsigned)tid; e < E; e += 256u) {
                unsigned ed = eflat[e];
                unsigned i = ed >> 12;
                unsigned j = ed & 4095u;
                if ((accS[i >> 6] >> (i & 63)) & 1ull)
                    atomicOr((unsigned*)&supS[j >> 6] + ((j >> 5) & 1u),
                             1u << (j & 31u));
            }
            __syncthreads();
            if (tid < 64) {
                int lo = tid << 6;
                u64 vmask = 0ull;
                if (lo < M) {
                    int nr = M - lo;
                    vmask = (nr >= 64) ? ~0ull : ((1ull << nr) - 1ull);
                }
                u64 na = vmask & ~supS[tid];
                if (na != accS[tid]) { accS[tid] = na; s_changed = 1; }
            }
            __syncthreads();
            if (s_changed == 0) break;
        }

        // ---- truncate to first MAXOUT accepts, expand to sel ----------------
        if (wv == 0) {
            u64 aw = accS[lane];
            int pc = __builtin_popcountll(aw);
            int scan = pc;
#pragma unroll
            for (int d = 1; d < 64; d <<= 1) {
                int t = __shfl_up(scan, d);
                if (lane >= d) scan += t;
            }
            int pos = scan - pc;                    // exclusive prefix
            int total = __shfl(scan, 63);
            int cnt = total < MAXOUT ? total : MAXOUT;
            int kept = MAXOUT - pos;
            kept = kept < 0 ? 0 : (kept > pc ? pc : kept);
            for (int t = 0; t < pc - kept; ++t)     // drop highest-index bits
                aw &= ~(0x8000000000000000ull >> __builtin_clzll(aw));
            while (aw) {
                int r = __builtin_ctzll(aw);
                aw &= aw - 1;
                sel[pos++] = (lane << 6) + r;
            }
            if (lane == 0) s_cnt = cnt;
        }
    } else {
        // ---------- fallback: exact serial recompute (overflow-safe) --------
        const float4* c4 = (const float4*)(cand + (size_t)b * KPRE * 4);
        for (int k = tid; k < KPRE; k += 256) {
            float4 v = c4[k];
            bxF[k] = v;
            sarF[k] = (v.y - v.x) * (v.w - v.z);
        }
        __syncthreads();
        if (wv == 0) {
            auto iougt = [&](float4 A, float aA, float4 Bq, float aB) -> bool {
#pragma clang fp contract(off)
                float iw = fminf(A.y, Bq.y) - fmaxf(A.x, Bq.x);
                iw = fmaxf(iw, 0.0f);
                float ih = fminf(A.w, Bq.w) - fmaxf(A.z, Bq.z);
                ih = fmaxf(ih, 0.0f);
                float inter = iw * ih;
                float uni = aA + aB - inter;
                return inter / fmaxf(uni, 1e-8f) > 0.7f;
            };
            u64 accReg = 0ull;
            int cnt = 0;
            for (int c = 0; c < nchunks && cnt < MAXOUT; ++c) {
                int r = (c << 6) + lane;
                bool valid = r < M;
                float4 bq = valid ? bxF[r] : make_float4(0.f, 0.f, 0.f, 0.f);
                float aq = valid ? sarF[r] : 0.f;
                u64 inT = 0ull;
                for (int i2 = 0; i2 < 64; ++i2) {
                    if (valid && i2 < lane) {
                        int ri = (c << 6) + i2;
                        if (iougt(bxF[ri], sarF[ri], bq, aq)) inT |= 1ull << i2;
                    }
                }
                bool supb = false;
                for (int cc = 0; cc < c; ++cc) {
                    u64 aw = readlane64(accReg, cc);
                    while (aw) {
                        int rb = __builtin_ctzll(aw);
                        aw &= aw - 1;
                        int ia = (cc << 6) + rb;
                        if (valid && iougt(bxF[ia], sarF[ia], bq, aq)) supb = true;
                    }
                }
                u64 live = __ballot(valid && !supb);
                u64 am = 0ull;
                while (live) {
                    u64 pred = __ballot((inT & live) != 0ull);
                    u64 acc = live & ~pred;
                    u64 sup = __ballot((inT & acc) != 0ull);
                    am |= acc;
                    live &= ~(acc | sup);
                }
                int pc = __builtin_popcountll(am);
                if (cnt + pc >= MAXOUT) {
                    int drop = cnt + pc - MAXOUT;
                    for (int t = 0; t < drop; ++t)
                        am &= ~(0x8000000000000000ull >> __builtin_clzll(am));
                    pc = MAXOUT - cnt;
                }
                if (lane == 0) {
                    u64 tmp = am;
                    int p = cnt;
                    while (tmp) {
                        int rr = __builtin_ctzll(tmp);
                        tmp &= tmp - 1;
                        sel[p++] = (c << 6) + rr;
                    }
                }
                if (lane == c) accReg |= am;
                cnt += pc;
            }
            if (lane == 0) s_cnt = cnt;
        }
    }
    __syncthreads();

    const int cntF = s_cnt;
    const float4* c4o = (const float4*)(cand + (size_t)b * KPRE * 4);
    float4* o4 = (float4*)(out + (size_t)b * MAXOUT * 4);
    for (int r = tid; r < MAXOUT; r += 256) {
        float4 v = make_float4(0.0f, 0.0f, 0.0f, 0.0f);
        if (r < cntF) v = c4o[sel[r]];
        o4[r] = v;
    }
}

// ---------------- launch ------------------------------------------------------
extern "C" void kernel_launch(void* const* d_in, const int* in_sizes, int n_in,
                              void* d_out, int out_size, void* d_ws, size_t ws_size,
                              hipStream_t stream) {
    const float* score   = (const float*)d_in[0];
    const float* delta   = (const float*)d_in[1];
    const float* anchors = (const float*)d_in[2];
    float* out = (float*)d_out;

    uint8_t* w8 = (uint8_t*)d_ws;
    unsigned* phist = (unsigned*)(w8 + 0);        // 8 x 8 x 4096 u32 (1 MB, pure writes)
    unsigned* start = (unsigned*)(w8 + 1048576);  // 8 x 4096 u32
    unsigned* bcnt  = (unsigned*)(w8 + 1179648);  // 8 x 4096 u32 (zeroed by k_cut)
    unsigned* meta  = (unsigned*)(w8 + 1310720);  // cut[8] | P[8] | M[8]
    unsigned* ecnt  = (unsigned*)(w8 + 1310848);  // 8 x 64 u32 (zeroed by k_cut)
    u64* keys       = (u64*)(w8 + 1312928);       // 8 x 4224 u64
    float* cand     = (float*)(w8 + 1583264);     // 8 x 4000 x 4 f32
    unsigned* ebuf  = (unsigned*)(w8 + 2095264);  // 8 x 64 x 2048 u32 (4 MB)

    k_hist<<<dim3(HBLK, NB), 256, 0, stream>>>(score, phist);
    k_cut<<<NB, 64, 0, stream>>>(phist, start, meta, ecnt, bcnt);
    k_collect<<<dim3(32, NB), 256, 0, stream>>>(score, meta, start, bcnt, keys);
    k_rank_decode<<<dim3((KEYCAP + 255) / 256, NB), 256, 0, stream>>>(keys, start, meta,
                                                                      delta, anchors, cand);
    k_geo<<<dim3(GTASKS / 4, NB, 2), 256, 0, stream>>>(cand, ecnt, ebuf);
    k_nms<<<NB, 256, 0, stream>>>(cand, ecnt, ebuf, meta, out);
}